// Round 3
// baseline (357.370 us; speedup 1.0000x reference)
//
#include <hip/hip_runtime.h>

// Embedding gather, inverted: stream W once (coalesced), scatter to out.
//   x: [16384] int32 token ids
//   W: [DIMS=1024, TOKENS=50257] f32 row-major (token vector = COLUMN of W)
//   out: [16384, 1024] f32
//
// R2 lessons: harness poison/restore is a fixed ~200us inside the timed graph;
// my chain was ~150us (main ~110 + 4 serialized tiny kernels). This round:
//  - 256-id windows: 1KB coalesced row segments (W rows are 4B-aligned only,
//    50257 odd, so scalar dword loads; misalign overfetch drops to ~1.13x).
//  - grid(dchunk=16, w=197): linear id = w*16+dchunk, XCD = id%8 = dchunk%8
//    independent of w -> adjacent-w blocks share an XCD L2 and reuse the
//    straddled boundary lines.
//  - LDS tile [64 dims x 256 ids] pitch 257: stage banks = c%32 (2-way, free),
//    scatter-read banks = (d+j)%32 (2-way, free). 64.25KB -> 2 blocks/CU.
//  - whole counting-sort fused into ONE single-block kernel (LDS hist + scan +
//    LDS-atomic scatter), emitting packed (pos<<8 | col) -> 2 graph nodes.

#define DIMS    1024
#define TOKENS  50257
#define WBITS   8
#define WSIZE   256
#define NW      ((TOKENS + WSIZE - 1) / WSIZE)   // 197 windows

// One block, 1024 threads: histogram -> scan -> stable-ish scatter.
// offs[NW+1] = window start offsets into packed[]; packed = (src_pos<<8)|(tok&255).
__global__ __launch_bounds__(1024) void prepass_kernel(
    const int* __restrict__ x, int n,
    int* __restrict__ offs, int* __restrict__ packed)
{
    __shared__ int hist[NW];
    __shared__ int curs[NW];
    __shared__ int s[256];
    const int t = threadIdx.x;

    if (t < NW) hist[t] = 0;
    __syncthreads();

    for (int i = t; i < n; i += 1024)
        atomicAdd(&hist[x[i] >> WBITS], 1);
    __syncthreads();

    // Hillis-Steele inclusive scan over 256 slots (NW=197 padded with 0)
    if (t < 256) s[t] = (t < NW) ? hist[t] : 0;
    __syncthreads();
    for (int off = 1; off < 256; off <<= 1) {
        int v = (t < 256 && t >= off) ? s[t - off] : 0;
        __syncthreads();
        if (t < 256) s[t] += v;
        __syncthreads();
    }
    if (t < NW) {
        offs[t + 1] = s[t];            // inclusive prefix
        curs[t]     = s[t] - hist[t];  // exclusive prefix = write head
    }
    if (t == 0) offs[0] = 0;
    __syncthreads();

    for (int i = t; i < n; i += 1024) {
        int tok = x[i];
        int p = atomicAdd(&curs[tok >> WBITS], 1);
        packed[p] = (i << 8) | (tok & (WSIZE - 1));
    }
}

// Block (dchunk=blockIdx.x, w=blockIdx.y): stage W[dbase:+64, w*256:+256] into
// LDS (coalesced), then write each resident token's 64 dims contiguously.
__global__ __launch_bounds__(256) void embed_main(
    const float* __restrict__ W,
    const int* __restrict__ offs,
    const int* __restrict__ packed,
    float* __restrict__ out)
{
    __shared__ float tile[64 * 257];             // [dim_row][id_col], pitch 257
    const int dchunk = blockIdx.x;
    const int w      = blockIdx.y;
    const int dbase  = dchunk * 64;
    const int id0    = w * WSIZE;
    const int t      = threadIdx.x;

    // Stage: thread t = column t (0..255), all 64 rows. Wave reads 256B
    // contiguous per row; 4 waves cover the 1KB row segment.
    const int id = id0 + t;
    if (w != NW - 1) {
        const float* __restrict__ p = W + (size_t)dbase * TOKENS + id;
        #pragma unroll 16
        for (int r = 0; r < 64; ++r)
            tile[r * 257 + t] = p[(size_t)r * TOKENS];
    } else {
        const bool ok = (id < TOKENS);
        const float* __restrict__ p = W + (size_t)dbase * TOKENS + (ok ? id : 0);
        #pragma unroll 16
        for (int r = 0; r < 64; ++r)
            tile[r * 257 + t] = ok ? p[(size_t)r * TOKENS] : 0.0f;
    }
    __syncthreads();

    const int beg = offs[w];
    const int nn  = offs[w + 1] - beg;
    const int d   = t & 63;                      // lanes sweep dims -> 256B store
    const int jo  = t >> 6;                      // 4 tokens per iteration
    for (int jb = 0; jb < nn; jb += 4) {
        int j = jb + jo;
        if (j < nn) {
            int pk  = packed[beg + j];           // wave-uniform -> broadcast
            int col = pk & (WSIZE - 1);
            int pos = pk >> 8;
            out[(size_t)pos * DIMS + dbase + d] = tile[d * 257 + col];
        }
    }
}

extern "C" void kernel_launch(void* const* d_in, const int* in_sizes, int n_in,
                              void* d_out, int out_size, void* d_ws, size_t ws_size,
                              hipStream_t stream) {
    const int*   x = (const int*)d_in[0];     // [16384]
    const float* W = (const float*)d_in[1];   // [1024, 50257]
    float*     out = (float*)d_out;

    const int n = in_sizes[0];                // 16384

    int* offs   = (int*)d_ws;                 // NW+1
    int* packed = offs + (NW + 1);            // n

    prepass_kernel<<<1, 1024, 0, stream>>>(x, n, offs, packed);

    dim3 grid(DIMS / 64, NW);                 // (16, 197); XCD = dchunk%8
    embed_main<<<grid, 256, 0, stream>>>(W, offs, packed, out);
}